// Round 3
// baseline (223.908 us; speedup 1.0000x reference)
//
#include <hip/hip_runtime.h>
#include <hip/hip_bf16.h>

typedef unsigned short u16;
typedef unsigned int u32;
typedef __attribute__((ext_vector_type(8))) short short8;   // 8 x bf16 frag
typedef __attribute__((ext_vector_type(4))) short short4v;  // 4 x bf16 pack
typedef __attribute__((ext_vector_type(16))) float f32x16;  // 32x32 acc
typedef __attribute__((ext_vector_type(4))) float f32x4;    // 16x16 acc

#define MFMA32 __builtin_amdgcn_mfma_f32_32x32x16_bf16
#define MFMA16 __builtin_amdgcn_mfma_f32_16x16x32_bf16

#define NSEQ 4096
#define CD 256
// (1/sqrt(256)) * log2(e) = 0.0625 * 1.4426950408889634  -- EXACT.
#define CF 0.09016844005556021f

__device__ __forceinline__ u16 f2bf(float f) {
  u32 u = __float_as_uint(f);
  u += 0x7fffu + ((u >> 16) & 1u);  // RNE
  return (u16)(u >> 16);
}
__device__ __forceinline__ float bf2f(short s) {
  return __uint_as_float(((u32)(u16)s) << 16);
}
// HW packed f32x2 -> bf16x2 (gfx950 v_cvt_pk_bf16_f32), RNE
__device__ __forceinline__ u32 pk2bf(float a, float b) {
  union {
    __hip_bfloat162 h;
    u32 u;
  } cv;
  cv.h = __float22bfloat162_rn(make_float2(a, b));
  return cv.u;
}
// async global -> LDS DMA, 16B per lane; LDS dest = wave-uniform base + lane*16
__device__ __forceinline__ void async16(const void* g, void* l) {
  __builtin_amdgcn_global_load_lds(
      (const __attribute__((address_space(1))) u32*)g,
      (__attribute__((address_space(3))) u32*)l, 16, 0, 0);
}

// ---------------------------------------------------------------------------
// transpose-cast x: (b, 256, 4096) f32 -> x_t (b, 4096, 256) bf16
// + folded weight cast (1024 blocks x 256 weight elems = exactly 768*256+256*256)
// ---------------------------------------------------------------------------
__global__ __launch_bounds__(256) void xpose_cast(const float* __restrict__ x,
                                                  u16* __restrict__ x_t,
                                                  const float* __restrict__ qkv_w,
                                                  const float* __restrict__ out_w,
                                                  u16* __restrict__ wq,
                                                  u16* __restrict__ wo) {
  __shared__ float tile[64][65];
  const int t = threadIdx.x;
  // ---- weight cast slice ----
  {
    int lin = blockIdx.x + 64 * (blockIdx.y + 4 * blockIdx.z);
    int widx = lin * 256 + t;
    if (widx < 768 * CD)
      wq[widx] = f2bf(qkv_w[widx]);
    else
      wo[widx - 768 * CD] = f2bf(out_w[widx - 768 * CD]);
  }
  // ---- transpose-cast ----
  const int b = blockIdx.z;
  const int n0 = blockIdx.x * 64, c0 = blockIdx.y * 64;
  const float* xb = x + (size_t)b * CD * NSEQ;
  const int cr = t >> 4, nc4 = (t & 15) * 4;
#pragma unroll
  for (int i = 0; i < 4; ++i) {
    int c = cr + 16 * i;
    float4 v = *(const float4*)(xb + (size_t)(c0 + c) * NSEQ + n0 + nc4);
    tile[c][nc4 + 0] = v.x;
    tile[c][nc4 + 1] = v.y;
    tile[c][nc4 + 2] = v.z;
    tile[c][nc4 + 3] = v.w;
  }
  __syncthreads();
  const int n = t & 63, cc = (t >> 6) * 16;
  u16* dst = x_t + (size_t)b * NSEQ * CD + (size_t)(n0 + n) * CD + c0 + cc;
#pragma unroll
  for (int j = 0; j < 4; ++j) {
    short4v pv;
#pragma unroll
    for (int r = 0; r < 4; ++r) pv[r] = (short)f2bf(tile[cc + 4 * j + r][n]);
    *(short4v*)(dst + 4 * j) = pv;
  }
}

// ---------------------------------------------------------------------------
// QKV projection, 128x128 tile, 512 threads (8 waves), 32x32x16 MFMA.
// (unchanged)
// ---------------------------------------------------------------------------
__global__ __launch_bounds__(512, 1) void qkv_gemm3(
    const u16* __restrict__ wq, const float* __restrict__ qkv_b,
    const u16* __restrict__ x_t, u16* __restrict__ q_t, u16* __restrict__ k_t,
    u16* __restrict__ v_) {
  __shared__ u16 __align__(16) Wls[128 * 256];
  __shared__ u16 __align__(16) Bls[128 * 256];
  const int t = threadIdx.x, w = t >> 6, lane = t & 63;
  const int l31 = lane & 31, l5 = lane >> 5;
  const int os = w & 3, nh = w >> 2;
  const int n0 = blockIdx.x * 128, o0 = blockIdx.y * 128, b = blockIdx.z;
  const u16* Xb = x_t + (size_t)b * NSEQ * CD;
#pragma unroll
  for (int j = 0; j < 8; ++j) {
    int r = w * 16 + j * 2 + l5;
    async16(wq + (size_t)(o0 + r) * CD + ((l31 ^ (r & 7)) * 8),
            Wls + (w * 16 + j * 2) * 256);
    async16(Xb + (size_t)(n0 + r) * CD + ((l31 ^ (r & 7)) * 8),
            Bls + (w * 16 + j * 2) * 256);
  }
  __builtin_amdgcn_s_waitcnt(0);
  __syncthreads();
  f32x16 acc0, acc1;
#pragma unroll
  for (int i = 0; i < 16; ++i) {
    acc0[i] = 0.f;
    acc1[i] = 0.f;
  }
  const int ra = os * 32 + l31;
  const int rb0 = nh * 64 + l31, rb1 = rb0 + 32;
#pragma unroll
  for (int kc = 0; kc < 16; ++kc) {
    short8 a = *(const short8*)(Wls + ra * 256 + (((kc * 2 + l5) ^ (ra & 7)) * 8));
    short8 b0 = *(const short8*)(Bls + rb0 * 256 + (((kc * 2 + l5) ^ (rb0 & 7)) * 8));
    short8 b1 = *(const short8*)(Bls + rb1 * 256 + (((kc * 2 + l5) ^ (rb1 & 7)) * 8));
    acc0 = MFMA32(a, b0, acc0, 0, 0, 0);
    acc1 = MFMA32(a, b1, acc1, 0, 0, 0);
  }
  const int otype = blockIdx.y >> 1;  // 0=Q 1=K 2=V
  const int obase = o0 + os * 32;
#pragma unroll
  for (int na = 0; na < 2; ++na) {
    f32x16& acc = na ? acc1 : acc0;
    const int n_g = n0 + nh * 64 + na * 32 + l31;
    if (otype < 2) {
      u16* dst = (otype == 0 ? q_t : k_t) + (size_t)b * NSEQ * CD +
                 (size_t)n_g * CD + (obase - otype * 256);
#pragma unroll
      for (int g = 0; g < 4; ++g) {
        float4 bv = *(const float4*)(qkv_b + obase + g * 8 + l5 * 4);
        const float* bp = (const float*)&bv;
        short4v pk;
#pragma unroll
        for (int r = 0; r < 4; ++r) pk[r] = (short)f2bf(acc[g * 4 + r] + bp[r]);
        *(short4v*)(dst + g * 8 + l5 * 4) = pk;
      }
    } else {
      u16* dst = v_ + (size_t)b * CD * NSEQ;
#pragma unroll
      for (int g = 0; g < 4; ++g) {
        float4 bv = *(const float4*)(qkv_b + obase + g * 8 + l5 * 4);
        const float* bp = (const float*)&bv;
#pragma unroll
        for (int r = 0; r < 4; ++r) {
          int c = obase - 512 + g * 8 + l5 * 4 + r;
          dst[(size_t)c * NSEQ + n_g] = f2bf(acc[g * 4 + r] + bp[r]);
        }
      }
    }
  }
}

// ---------------------------------------------------------------------------
// Flash attention v9: occupancy-doubling restructure. 512-thread blocks
// (8 waves), each wave owns a 16-m strip on 16x16x32 MFMA -> per-wave state
// halves (O acc 64 regs, Q frags 32 regs); __launch_bounds__(512,4) targets
// <=128 regs/wave => 2 blocks/CU = 16 waves/CU = 4 waves/SIMD (was 2).
// Same grid (512 = 4b x 4q x 32 mblk x 128 m), same K/V LDS tiles + DMA
// layout (now staged by 8 waves, 4 DMAs/wave/tile), same double-buffer.
//   S : two INDEPENDENT 16x16 subtile chains (keys 0-15 / 16-31), K=256.
//   softmax: per-lane 8 scores + 2 shfl_xor (16,32) reduce across g-groups.
//   P -> B-frag: 8-shfl_xor 4x4-dword butterfly (xor16 pair-merge, xor32
//   type-exchange), index-verified against C layout col=l&15,row=(l>>4)*4+r
//   and A/B layout row/col=l&15, k=(l>>4)*8+j.
//   PV: O[256c x 16m] = 16 independent 16x16 subtile chains.
// T5 setprio around both MFMA clusters.
// ---------------------------------------------------------------------------
__global__ __launch_bounds__(512, 4) void flash9(const u16* __restrict__ q_t,
                                                 const u16* __restrict__ k_t,
                                                 const u16* __restrict__ v_,
                                                 u16* __restrict__ opart,
                                                 float2* __restrict__ ml) {
  __shared__ u16 __align__(16) Kls[2][32 * 256];  // [buf][n][c] swizzled
  __shared__ u16 __align__(16) Vls[2][128 * 64];  // [buf][c-pair rows]

  const int t = threadIdx.x, w = t >> 6, lane = t & 63;
  const int l31 = lane & 31, l5 = lane >> 5;
  const int l15 = lane & 15, g = lane >> 4;

  // XCD swizzle: xcd owns (b, quarter-pair) -> K/V/Q working set ~4MB in L2.
  const int linear = blockIdx.x;
  const int xcd = linear & 7, slot = linear >> 3;  // slot in [0,64)
  const int b = xcd >> 1;
  const int q = (xcd & 1) * 2 + (slot >> 5);  // key-quarter 0..3
  const int mblk = slot & 31;
  const int m0 = mblk * 128;
  const int nbase = q * 1024;

  const u16* Qb = q_t + (size_t)b * NSEQ * CD;
  const u16* Kb = k_t + (size_t)b * NSEQ * CD;
  const u16* Vb = v_ + (size_t)b * CD * NSEQ;

  const int mrow = m0 + w * 16 + l15;  // global query index (col = l15)

  // Q fragments in registers (B-operand for S), K=256: 8 x short8 = 32 VGPRs
  short8 qf[8];
#pragma unroll
  for (int kk = 0; kk < 8; ++kk)
    qf[kk] = *(const short8*)(Qb + (size_t)mrow * CD + kk * 32 + g * 8);

  // --- per-lane staging address constants ---
  // K: wave w stages rows w*4 + j*2 + l5 (2 rows per 1KB DMA, 2 DMAs)
  // V: paired-row layout: LDS row c2 (128 B) holds c = 2*c2 + (ch>>2),
  //    n-span (ch&3)*8..+8, phys chunk = ch ^ (c2&7). DMA lane covers
  //    row c2 = w*16 + j*8 + (lane>>3), phys chunk lane&7 (2 DMAs).
  const u16* ksrc[2];
#pragma unroll
  for (int j = 0; j < 2; ++j) {
    int kr = w * 4 + j * 2 + l5;
    ksrc[j] = Kb + (size_t)kr * CD + ((l31 ^ (kr & 7)) * 8);
  }
  const u16* vsrc[2];
#pragma unroll
  for (int j = 0; j < 2; ++j) {
    int c2 = w * 16 + j * 8 + (lane >> 3);
    int chl = (lane & 7) ^ (c2 & 7);
    int c = (c2 << 1) | (chl >> 2);
    vsrc[j] = Vb + (size_t)c * NSEQ + (chl & 3) * 8;
  }

  // stage tile 0 into buf 0
#pragma unroll
  for (int j = 0; j < 2; ++j) {
    async16(ksrc[j] + (size_t)nbase * CD, &Kls[0][(w * 4 + j * 2) * 256]);
    async16(vsrc[j] + nbase, &Vls[0][(w * 16 + j * 8) * 64]);
  }

  float mst = -3.0e38f, lst = 0.f;
  f32x4 oa[16];  // O[c = ct*16 + g*4 + r][m = l15]: 64 regs
#pragma unroll
  for (int i = 0; i < 16; ++i)
#pragma unroll
    for (int r = 0; r < 4; ++r) oa[i][r] = 0.f;

  // hoisted V read base: c2 = ct*8 + (l15>>1); phys = chl ^ (c2&7) is
  // ct-independent since ct*8 ≡ 0 (mod 8).
  const int vbase =
      (l15 >> 1) * 64 + (((((l15 & 1) << 2) | g) ^ ((l15 >> 1) & 7)) * 8);
  const int kx = l15 & 7;  // K chunk xor (same for both subtiles: (16+l15)&7)

  for (int tt = 0; tt < 32; ++tt) {
    const int cur = tt & 1;
    // drain: tile tt's DMA complete; prior reads of buf[cur] done
    __builtin_amdgcn_s_waitcnt(0);
    __syncthreads();
    if (tt + 1 < 32) {
      const int n0 = nbase + (tt + 1) * 32;
      const int nxt = cur ^ 1;
#pragma unroll
      for (int j = 0; j < 2; ++j) {
        async16(ksrc[j] + (size_t)n0 * CD, &Kls[nxt][(w * 4 + j * 2) * 256]);
        async16(vsrc[j] + n0, &Vls[nxt][(w * 16 + j * 8) * 64]);
      }
    }
    // ---- S = K . Q^T : two independent 16-key subtiles, K=256 ----
    f32x4 sa0, sa1;
#pragma unroll
    for (int r = 0; r < 4; ++r) {
      sa0[r] = 0.f;
      sa1[r] = 0.f;
    }
    __builtin_amdgcn_s_setprio(1);
#pragma unroll
    for (int kk = 0; kk < 8; ++kk) {
      const int ch = kk * 4 + g;  // logical chunk; xor affects low 3 bits
      short8 a0 = *(const short8*)(&Kls[cur][l15 * 256 + ((ch ^ kx) * 8)]);
      short8 a1 =
          *(const short8*)(&Kls[cur][(16 + l15) * 256 + ((ch ^ kx) * 8)]);
      sa0 = MFMA16(a0, qf[kk], sa0, 0, 0, 0);
      sa1 = MFMA16(a1, qf[kk], sa1, 0, 0, 0);
    }
    __builtin_amdgcn_s_setprio(0);
    // ---- softmax: lane holds 8 scores for m=l15 (keys 16t+4g+r);
    //      4 lanes per m merge via shfl_xor 16,32 ----
    float rm = fmaxf(fmaxf(fmaxf(sa0[0], sa0[1]), fmaxf(sa0[2], sa0[3])),
                     fmaxf(fmaxf(sa1[0], sa1[1]), fmaxf(sa1[2], sa1[3])));
    rm = fmaxf(rm, __shfl_xor(rm, 16));
    rm = fmaxf(rm, __shfl_xor(rm, 32));
    float mnew = fmaxf(mst, rm * CF);
    float al = exp2f(mst - mnew);
    mst = mnew;
    float p00 = exp2f(sa0[0] * CF - mnew), p01 = exp2f(sa0[1] * CF - mnew);
    float p02 = exp2f(sa0[2] * CF - mnew), p03 = exp2f(sa0[3] * CF - mnew);
    float p10 = exp2f(sa1[0] * CF - mnew), p11 = exp2f(sa1[1] * CF - mnew);
    float p12 = exp2f(sa1[2] * CF - mnew), p13 = exp2f(sa1[3] * CF - mnew);
    float ls = ((p00 + p01) + (p02 + p03)) + ((p10 + p11) + (p12 + p13));
    ls += __shfl_xor(ls, 16);
    ls += __shfl_xor(ls, 32);
    lst = lst * al + ls;
    // ---- rescale O only when the running max moved ----
    if (__ballot(al != 1.0f)) {
#pragma unroll
      for (int i = 0; i < 16; ++i)
#pragma unroll
        for (int r = 0; r < 4; ++r) oa[i][r] *= al;
    }
    // ---- P -> B-frag: 4x4 dword butterfly across g-groups ----
    // lane (g,m) holds dwords A0=(k 4g,4g+1) A1=(4g+2,4g+3) of subtile0,
    // B0/B1 of subtile1. Target lane g' needs keys 8g'..8g'+7 (j-ascending).
    u32 A0 = pk2bf(p00, p01), A1 = pk2bf(p02, p03);
    u32 B0 = pk2bf(p10, p11), B1 = pk2bf(p12, p13);
    const int g0 = g & 1, h = g >> 1;
    // step 1 (xor16): pair (2h,2h+1) assembles CA = W of g'=h for subtile0,
    // CB = W of g'=2+h for subtile1 (both lanes hold copies).
    u32 ea0 = (u32)__shfl_xor((int)A0, 16), ea1 = (u32)__shfl_xor((int)A1, 16);
    u32 eb0 = (u32)__shfl_xor((int)B0, 16), eb1 = (u32)__shfl_xor((int)B1, 16);
    u32 CA0 = g0 ? ea0 : A0, CA1 = g0 ? ea1 : A1;
    u32 CA2 = g0 ? A0 : ea0, CA3 = g0 ? A1 : ea1;
    u32 CB0 = g0 ? eb0 : B0, CB1 = g0 ? eb1 : B1;
    u32 CB2 = g0 ? B0 : eb0, CB3 = g0 ? B1 : eb1;
    // step 2 (xor32): send CA if h else CB; keep CB if h else CA;
    // final = own keep if g0==h else received.
    u32 s0 = h ? CA0 : CB0, s1 = h ? CA1 : CB1;
    u32 s2 = h ? CA2 : CB2, s3 = h ? CA3 : CB3;
    u32 r0 = (u32)__shfl_xor((int)s0, 32), r1 = (u32)__shfl_xor((int)s1, 32);
    u32 r2 = (u32)__shfl_xor((int)s2, 32), r3 = (u32)__shfl_xor((int)s3, 32);
    u32 k0 = h ? CB0 : CA0, k1 = h ? CB1 : CA1;
    u32 k2 = h ? CB2 : CA2, k3 = h ? CB3 : CA3;
    const bool own = (g0 == h);
    union {
      u32 u[4];
      short8 s8;
    } pfv;
    pfv.u[0] = own ? k0 : r0;
    pfv.u[1] = own ? k1 : r1;
    pfv.u[2] = own ? k2 : r2;
    pfv.u[3] = own ? k3 : r3;
    short8 pf = pfv.s8;
    // ---- O += V . P : 16 independent 16c subtiles x 32 keys (K=32) ----
    __builtin_amdgcn_s_setprio(1);
#pragma unroll
    for (int ct = 0; ct < 16; ++ct) {
      short8 vf = *(const short8*)(&Vls[cur][ct * 512 + vbase]);
      oa[ct] = MFMA16(vf, pf, oa[ct], 0, 0, 0);
    }
    __builtin_amdgcn_s_setprio(0);
  }

  // ---- finalize: per-stream normalized O -> bf16; (m,l) for merge ----
  float inv = 1.0f / lst;
  u16* dst = opart + ((size_t)(q * 4 + b) * NSEQ + mrow) * CD;
#pragma unroll
  for (int ct = 0; ct < 16; ++ct) {
    short4v pk;
#pragma unroll
    for (int r = 0; r < 4; ++r) pk[r] = (short)f2bf(oa[ct][r] * inv);
    *(short4v*)(dst + ct * 16 + g * 4) = pk;
  }
  if (lane < 16)
    ml[(size_t)(q * 4 + b) * NSEQ + mrow] = make_float2(mst, lst);
}

// ---------------------------------------------------------------------------
// out projection + 4-stream split-key merge folded into B-tile staging.
// (unchanged)
// ---------------------------------------------------------------------------
__global__ __launch_bounds__(512, 1) void out_gemm6(
    const u16* __restrict__ wo, const float* __restrict__ out_b,
    const u16* __restrict__ opart, const float2* __restrict__ ml,
    float* __restrict__ out) {
  __shared__ u16 __align__(16) Wls[128 * 256];
  __shared__ u16 __align__(16) Bls[128 * 256];
  const int t = threadIdx.x, w = t >> 6, lane = t & 63;
  const int l31 = lane & 31, l5 = lane >> 5;
  const int os = w & 3, nh = w >> 2;
  const int n0 = blockIdx.x * 128, o0 = blockIdx.y * 128, b = blockIdx.z;
#pragma unroll
  for (int j = 0; j < 8; ++j) {
    int r = w * 16 + j * 2 + l5;
    async16(wo + (size_t)(o0 + r) * CD + ((l31 ^ (r & 7)) * 8),
            Wls + (w * 16 + j * 2) * 256);
  }
#pragma unroll
  for (int i = 0; i < 8; ++i) {
    int idx = i * 512 + t;
    int r = idx >> 5, p = idx & 31;
    int n = n0 + r;
    float2 st[4];
#pragma unroll
    for (int qq = 0; qq < 4; ++qq) st[qq] = ml[(size_t)(qq * 4 + b) * NSEQ + n];
    float M = fmaxf(fmaxf(st[0].x, st[1].x), fmaxf(st[2].x, st[3].x));
    float wt[4], tot = 0.f;
#pragma unroll
    for (int qq = 0; qq < 4; ++qq) {
      wt[qq] = st[qq].y * exp2f(st[qq].x - M);
      tot += wt[qq];
    }
    float inv = 1.0f / tot;
    float acc[8] = {};
#pragma unroll
    for (int qq = 0; qq < 4; ++qq) {
      float wq_ = wt[qq] * inv;
      short8 xq =
          *(const short8*)(opart + ((size_t)(qq * 4 + b) * NSEQ + n) * CD + p * 8);
#pragma unroll
      for (int e = 0; e < 8; ++e) acc[e] += wq_ * bf2f(xq[e]);
    }
    short8 om;
#pragma unroll
    for (int e = 0; e < 8; ++e) om[e] = (short)f2bf(acc[e]);
    *(short8*)(Bls + r * 256 + ((p ^ (r & 7)) * 8)) = om;
  }
  __builtin_amdgcn_s_waitcnt(0);
  __syncthreads();
  f32x16 acc0, acc1;
#pragma unroll
  for (int i = 0; i < 16; ++i) {
    acc0[i] = 0.f;
    acc1[i] = 0.f;
  }
  const int ra = os * 32 + l31;
  const int rb0 = nh * 64 + l31, rb1 = rb0 + 32;
#pragma unroll
  for (int kc = 0; kc < 16; ++kc) {
    short8 a = *(const short8*)(Wls + ra * 256 + (((kc * 2 + l5) ^ (ra & 7)) * 8));
    short8 b0 = *(const short8*)(Bls + rb0 * 256 + (((kc * 2 + l5) ^ (rb0 & 7)) * 8));
    short8 b1 = *(const short8*)(Bls + rb1 * 256 + (((kc * 2 + l5) ^ (rb1 & 7)) * 8));
    acc0 = MFMA32(a, b0, acc0, 0, 0, 0);
    acc1 = MFMA32(a, b1, acc1, 0, 0, 0);
  }
  const int obase = o0 + os * 32;
#pragma unroll
  for (int na = 0; na < 2; ++na) {
    f32x16& acc = na ? acc1 : acc0;
    const int n_g = n0 + nh * 64 + na * 32 + l31;
#pragma unroll
    for (int g = 0; g < 4; ++g) {
      float4 bv = *(const float4*)(out_b + obase + g * 8 + l5 * 4);
      const float* bp = (const float*)&bv;
#pragma unroll
      for (int r = 0; r < 4; ++r) {
        int o = obase + g * 8 + l5 * 4 + r;
        out[((size_t)b * CD + o) * NSEQ + n_g] = acc[g * 4 + r] + bp[r];
      }
    }
  }
}

// ---------------------------------------------------------------------------
extern "C" void kernel_launch(void* const* d_in, const int* in_sizes, int n_in,
                              void* d_out, int out_size, void* d_ws,
                              size_t ws_size, hipStream_t stream) {
  const float* x = (const float*)d_in[0];
  const float* qkv_w = (const float*)d_in[1];
  const float* qkv_b = (const float*)d_in[2];
  const float* out_w = (const float*)d_in[3];
  const float* out_b = (const float*)d_in[4];
  float* out = (float*)d_out;

  const size_t SZ = (size_t)4 * NSEQ * CD;  // elems per (b,4096,256) bf16
  u16* x_t = (u16*)d_ws;
  u16* q_t = x_t + SZ;
  u16* k_t = q_t + SZ;
  u16* v_ = k_t + SZ;
  u16* opart = v_ + SZ;              // 4 key-stream quarters, 4*SZ
  u16* wq = opart + 4 * SZ;          // 768*256
  u16* wo = wq + 768 * CD;           // 256*256
  float2* ml = (float2*)(wo + CD * CD);  // 4*4*4096 float2

  xpose_cast<<<dim3(64, 4, 4), dim3(256), 0, stream>>>(x, x_t, qkv_w, out_w,
                                                       wq, wo);
  qkv_gemm3<<<dim3(32, 6, 4), dim3(512), 0, stream>>>(wq, qkv_b, x_t, q_t, k_t,
                                                      v_);
  flash9<<<dim3(512), dim3(512), 0, stream>>>(q_t, k_t, v_, opart, ml);
  out_gemm6<<<dim3(32, 2, 4), dim3(512), 0, stream>>>(wo, out_b, opart, ml,
                                                      out);
}